// Round 1
// 679.316 us; speedup vs baseline: 1.0938x; 1.0938x over previous
//
#include <hip/hip_runtime.h>
#include <stdint.h>

#define F_DIM 321
#define O_DIM 720
#define I_DIM 512
#define B_DIM 32
#define G_F 8   // f's per block in the GEMM kernel

typedef __attribute__((ext_vector_type(8))) short short8;   // 8 bf16 = 4 VGPRs
typedef __attribute__((ext_vector_type(4))) float f32x4;
typedef __attribute__((ext_vector_type(4))) uint32_t u32x4;
typedef __attribute__((ext_vector_type(2))) uint32_t u32x2;

// Round-to-nearest-even fp32 -> bf16, packed pairwise into a dword.
__device__ __forceinline__ uint32_t rne_pack2(float lo, float hi) {
  uint32_t a = __builtin_bit_cast(uint32_t, lo);
  uint32_t b = __builtin_bit_cast(uint32_t, hi);
  a += 0x7FFFu + ((a >> 16) & 1u);
  b += 0x7FFFu + ((b >> 16) & 1u);
  return (a >> 16) | (b & 0xFFFF0000u);
}

// Kernel 1 (unchanged, verified): xn = x*inv + shift, bf16, A-frag-native:
// ws[f][iblk(64)][b(32)] = 16B = 8 consecutive i for that (b,f).
__global__ void __launch_bounds__(256) xn_pack_kernel(
    const float* __restrict__ x, const float* __restrict__ gamma,
    const float* __restrict__ beta, const float* __restrict__ rmean,
    const float* __restrict__ rvar, u32x4* __restrict__ ws) {
  __shared__ float tile[8 * F_DIM];
  const int iblk = blockIdx.x;  // 0..63
  const int b    = blockIdx.y;  // 0..31
  const float* src = x + ((size_t)b * I_DIM + (size_t)iblk * 8) * F_DIM;
  for (int idx = threadIdx.x; idx < 8 * F_DIM; idx += 256)
    tile[idx] = src[idx];
  __syncthreads();
  for (int f = threadIdx.x; f < F_DIM; f += 256) {
    float inv = gamma[f] * rsqrtf(rvar[f] + 1e-5f);
    float sh  = beta[f] - rmean[f] * inv;
    float v[8];
#pragma unroll
    for (int j = 0; j < 8; ++j) v[j] = fmaf(tile[j * F_DIM + f], inv, sh);
    u32x4 pk;
    pk.x = rne_pack2(v[0], v[1]);
    pk.y = rne_pack2(v[2], v[3]);
    pk.z = rne_pack2(v[4], v[5]);
    pk.w = rne_pack2(v[6], v[7]);
    ws[(size_t)f * 2048 + iblk * 32 + b] = pk;
  }
}

// Kernel 2 v3: FULLY-DENSE W staging.
// Theory: R1 (direct 32-B/lane frag loads, ~2 TB/s) and R2 (LDS-staged but
// 32-B-stride lanes) share one invariant: every wave load instruction
// touches 2x the minimum cache lines (64 B used per 128-B line). v3 loads
// the 64-KB W tile FLAT: thread t, step j reads 16 B at float4-index
// j*256+t -> each wave instr is 1 KB contiguous (8 lines, 100% dense).
//
// LDS granule shrinks to 8 B (4 bf16 = 4 consecutive i). Layout:
//   granule g = o*128 + i/4, byte = 8*g ^ ((o&7)<<4)   (3-bit XOR swizzle)
// - staging ds_write_b64: wave covers 512 contiguous bytes (XOR permutes
//   16-B chunks within 128-B groups -> same set) = conflict-free dense.
// - compute ds_read_b128 at (o*1024 + kk*64 + quad*16)^((o&7)<<4): lanes'
//   chunk-class = ((kk&1)*4+quad)^(t16&7) -> exactly 8 lanes per class
//   (even over all 32 banks; unswizzled would be 16-way conflicted).
__global__ void __launch_bounds__(256) linear_bn_kernel(
    const float* __restrict__ Wt, const float* __restrict__ bias,
    const u32x4* __restrict__ xn, float* __restrict__ out) {
  __shared__ u32x4 lds4[2048];  // 32 KB bf16 W-tile: 32 o x 512 i
  char* ldsb = (char*)lds4;
  const int tid  = threadIdx.x;
  const int lane = tid & 63;
  const int wv   = tid >> 6;
  const int quad = lane >> 4;
  const int t16  = lane & 15;
  const int mtile = wv & 1;        // compute: b-half
  const int ntile = wv >> 1;       // compute: o-half

  // XCD-chunked bijective remap (m204 form; nwg=943=8*117+7): XCD k gets
  // ~118 consecutive work ids -> blocks sharing an f-group (same xn slice)
  // land on 1-2 XCDs instead of 8 -> xn L2-resident per XCD.
  const int d   = blockIdx.y * 23 + blockIdx.x;
  const int xcd = d & 7, idx = d >> 3;
  const int w   = (xcd < 7) ? xcd * 118 + idx : 826 + idx;
  const int bx  = w % 23;
  const int by  = w / 23;

  const int o0 = bx * 32;
  const int fb = by * G_F;
  const int nf = min(G_F, F_DIM - fb);   // tail group (fb=320) has nf=1
  const int oC = o0 + ntile * 16 + t16;  // compute column (guarded)

  // staging coords: thread owns float4-column sc of rows {2j+shi}
  const int sc  = tid & 127;   // i/4 within the row (0..127)
  const int shi = tid >> 7;    // row parity (0/1)

  f32x4 acc[G_F];
#pragma unroll
  for (int ff = 0; ff < G_F; ++ff) {
    float bv = 0.0f;
    if (ff < nf && oC < O_DIM) bv = bias[(size_t)(fb + ff) * O_DIM + oC];
    acc[ff] = (f32x4){bv, bv, bv, bv};
  }

  u32x2 pk[16];
  auto stage_load = [&](int f) {
    const float* fbase = Wt + (size_t)f * (O_DIM * I_DIM) + sc * 4;
#pragma unroll
    for (int j = 0; j < 16; ++j) {
      // row clamp only bites for bx=22 (o 720..735 -> 719, L2-absorbed;
      // those B-frag rows feed only oC>=720 lanes, which are store-guarded)
      const int row = min(o0 + 2 * j + shi, O_DIM - 1);
      f32x4 a = *(const f32x4*)(fbase + (size_t)row * I_DIM);
      u32x2 p;
      p.x = rne_pack2(a.x, a.y);
      p.y = rne_pack2(a.z, a.w);
      pk[j] = p;
    }
  };

  stage_load(fb);
#pragma unroll
  for (int ff = 0; ff < G_F; ++ff) {
    if (ff >= nf) break;               // nf is block-uniform: barrier-safe
    __syncthreads();                   // LDS free (previous compute done)
#pragma unroll
    for (int j = 0; j < 16; ++j) {     // dense swizzled b64 writes
      const int o = 2 * j + shi;
      const int byte = ((o * 128 + sc) * 8) ^ ((o & 7) << 4);
      *(u32x2*)(ldsb + byte) = pk[j];
    }
    __syncthreads();
    if (ff + 1 < nf) stage_load(fb + ff + 1);  // prefetch overlaps compute
    const int f = fb + ff;
    const u32x4* xf = xn + (size_t)f * 2048 + mtile * 16 + t16;
    const int orow = ntile * 16 + t16;
    const int swz  = (t16 & 7) << 4;   // == (orow&7)<<4
#pragma unroll
    for (int kk = 0; kk < 16; ++kk) {
      u32x4 av = xf[(kk * 4 + quad) * 32];                      // A: L2-res
      u32x4 bv = *(const u32x4*)(
          ldsb + ((orow * 1024 + kk * 64 + quad * 16) ^ swz));  // even banks
      acc[ff] = __builtin_amdgcn_mfma_f32_16x16x32_bf16(
          __builtin_bit_cast(short8, av), __builtin_bit_cast(short8, bv),
          acc[ff], 0, 0, 0);
    }
  }

  // Epilogue: C/D col = t16 (o), row = quad*4+r (b). ff-inner store order
  // gives 8 consecutive f-dwords per (b,o) -> L2 merges into 32-B runs.
  if (oC < O_DIM) {
#pragma unroll
    for (int r = 0; r < 4; ++r) {
      const int brow = mtile * 16 + quad * 4 + r;
      float* po = out + ((size_t)brow * O_DIM + oC) * F_DIM + fb;
#pragma unroll
      for (int ff = 0; ff < G_F; ++ff)
        if (ff < nf) po[ff] = acc[ff][r];
    }
  }
}

extern "C" void kernel_launch(void* const* d_in, const int* in_sizes, int n_in,
                              void* d_out, int out_size, void* d_ws, size_t ws_size,
                              hipStream_t stream) {
  const float* x     = (const float*)d_in[0];
  const float* W     = (const float*)d_in[1];
  const float* b     = (const float*)d_in[2];
  const float* gamma = (const float*)d_in[3];
  const float* beta  = (const float*)d_in[4];
  const float* rmean = (const float*)d_in[5];
  const float* rvar  = (const float*)d_in[6];
  u32x4* ws = (u32x4*)d_ws;  // 321*2048*16 B = 10.5 MB << ws_size

  xn_pack_kernel<<<dim3(64, 32), 256, 0, stream>>>(x, gamma, beta, rmean, rvar, ws);
  linear_bn_kernel<<<dim3(23, 41), 256, 0, stream>>>(W, b, ws, (float*)d_out);
}